// Round 11
// baseline (136.016 us; speedup 1.0000x reference)
//
#include <hip/hip_runtime.h>
#include <math.h>

#define BATCH 64
#define DIM   640
#define MSP   100        // spatial M = 10*10
#define BT    128        // k_sums tile
#define NT2   5          // DIM / BT
#define NPAIR2 15        // 128-tile upper-tri pairs
#define NBLK2 960        // NPAIR2 * BATCH
#define WT    32         // k_write tile (wave-independent)
#define NTW   20         // DIM / WT
#define NPAIRW 210       // NTW*(NTW+1)/2
#define NBLKW  3392      // ceil(212/4) * 64 blocks, 4 wave-items each
#define PTRI  205120     // DIM*(DIM+1)/2
#define EPSV  1e-5f

// ws float-region offsets (floats). NOTHING needs zero-init: every location is
// plain-stored before it is read within the same call (poison-safe).
#define WS_D  0               // 40960: per-row norms (diag-block exports)
#define WS_SP 40960           // 204800: S partials [b][tile 0..4][slot 0..4][128]
#define WS_GP 245760          // 960: grand partials [b][pair 0..14]
// floats end at 246720; pad to 246784 -> byte 987136 (256-aligned)
#define XB_OFF 987136ull      // swizzled bf16 x: 2560 panels x 2048 shorts
// total ws ~11.5 MB
//
// Lessons encoded (R0..R10):
//  - cooperative launch / host API in kernel_launch breaks graph capture (R3/R4)
//  - device spin barriers + agent-scope atomics are latency-poisoned (R7: 2.2x)
//  - XCD-pinning batches (bid&7=XCD, 8 batches/XCD, data < 4MB L2): ~17us (R1->R2)
//  - LDS-staged prep fusion regresses (R9: 64KB LDS occupancy + serial loop)
//  - write pass is latency-bound: 3520 blk > 960 blk by 10us (R8); 32-tile = 64-tile (R10)
//  - kernels' pure work ~25us but kernels+overhead ~61us -> per-dispatch
//    overhead ~5-7us dominates => R11 cuts dispatches 3->2 WITHOUT R9's mistakes:
//    register-built frags from x (no LDS), slot-partial S/G (no init), per-wave
//    shuffle reductions in k_write (no barrier).
//
// xb layout: panel = 16 rows x 128 k, [c=ks*4+lq][lm=row%16][8 halves];
// frag read = lq*128+lm*8+ks*512 (1KB dense per wave-load).

typedef __attribute__((ext_vector_type(8))) short short8;
typedef __attribute__((ext_vector_type(4))) float f32x4;

__device__ __forceinline__ short f2bf(float f) {
    union { float f; unsigned u; } x; x.f = f;
    unsigned r = x.u + 0x7fffu + ((x.u >> 16) & 1u);
    return (short)(r >> 16);
}
__device__ __forceinline__ float bf2f(short h) {
    union { unsigned u; float f; } x; x.u = ((unsigned)(unsigned short)h) << 16;
    return x.f;
}

template <int NT_>
__device__ __forceinline__ void decode_pairN(int u, int& ti, int& tj) {
    ti = 0;
    while (u >= NT_ - ti) { u -= NT_ - ti; ++ti; }
    tj = ti + u;
}

// bid (0..959) -> (b, u, ti, tj), 128-tiles, XCD-pinned batches
__device__ __forceinline__ void decode_block128(int bid, int& b, int& u,
                                                int& ti, int& tj) {
    const int xcd = bid & 7;
    const int idx = bid >> 3;          // 0..119
    b = xcd + 8 * (idx & 7);           // fixed set of 8 batches per XCD
    u = idx >> 3;                      // 0..14
    decode_pairN<NT2>(u, ti, tj);
}

// Build one 16x32 bf16 fragment (panel m, k-step ks) for this lane directly
// from fp32 x; accumulates sum of squares of the ROUNDED values into nacc.
__device__ __forceinline__ short8 make_frag(const float* __restrict__ xrow,
                                            int ks, int lq, float& nacc) {
    float v[8];
#pragma unroll
    for (int e = 0; e < 8; ++e) v[e] = 0.f;
    if (ks < 3) {                              // k0 = ks*32+lq*8 <= 88 -> full 8
        const float* s = xrow + ks * 32 + lq * 8;
        float4 u0 = *(const float4*)(s);
        float4 u1 = *(const float4*)(s + 4);
        v[0] = u0.x; v[1] = u0.y; v[2] = u0.z; v[3] = u0.w;
        v[4] = u1.x; v[5] = u1.y; v[6] = u1.z; v[7] = u1.w;
    } else if (lq == 0) {                      // k0 = 96: only 96..99 valid
        float4 u0 = *(const float4*)(xrow + 96);
        v[0] = u0.x; v[1] = u0.y; v[2] = u0.z; v[3] = u0.w;
    }
    short8 h;
#pragma unroll
    for (int e = 0; e < 8; ++e) {
        short hb = f2bf(v[e]);
        float vr = bf2f(hb);
        nacc += vr * vr;
        h[e] = hb;
    }
    return h;
}

// Pass 1 (prep fused, register path): 960 blocks. Wave (wr,wc) owns a 64x64
// quadrant of a 128x128 tile. Frags built from x in registers; diag-block
// wc==0 waves export panels to xb + norms to D. sqrt-dcov -> S/G partials.
__global__ __launch_bounds__(256) void k_sums(const float* __restrict__ x,
                                              const float* __restrict__ tsc,
                                              float* __restrict__ ws) {
    __shared__ float sRow[BT];
    __shared__ float sCol[BT];

    int b, u, ti, tj;
    decode_block128(blockIdx.x, b, u, ti, tj);
    const int i0 = ti * BT, j0 = tj * BT;
    const int tid = threadIdx.x;
    short* xbg = (short*)((char*)ws + XB_OFF);

    if (tid < BT) { sRow[tid] = 0.f; sCol[tid] = 0.f; }

    const int wave = tid >> 6, lane = tid & 63;
    const int lm = lane & 15, lq = lane >> 4;
    const int r0 = (wave >> 1) * 64, c0 = (wave & 1) * 64;
    const int ra = i0 + r0, rb = j0 + c0;
    const bool diag = (ti == tj);
    const bool expw = diag && ((wave & 1) == 0);   // waves 0,2 export A panels

    const float* xba = x + ((size_t)b * DIM + ra + lm) * MSP;  // + 16m rows
    const float* xbb = x + ((size_t)b * DIM + rb + lm) * MSP;

    f32x4 acc[4][4] = {};
    float na[4] = {}, nb[4] = {};
#pragma unroll
    for (int ks = 0; ks < 4; ++ks) {
        short8 af[4], bf[4];
#pragma unroll
        for (int m = 0; m < 4; ++m) {
            af[m] = make_frag(xba + (size_t)(16 * m) * MSP, ks, lq, na[m]);
            if (expw)
                *(short8*)(xbg + (size_t)(b * 40 + ((ra >> 4) + m)) * 2048
                           + (ks * 4 + lq) * 128 + lm * 8) = af[m];
        }
#pragma unroll
        for (int n = 0; n < 4; ++n)
            bf[n] = make_frag(xbb + (size_t)(16 * n) * MSP, ks, lq, nb[n]);
#pragma unroll
        for (int m = 0; m < 4; ++m)
#pragma unroll
            for (int n = 0; n < 4; ++n)
                acc[m][n] = __builtin_amdgcn_mfma_f32_16x16x32_bf16(af[m], bf[n], acc[m][n], 0, 0, 0);
    }

    // finish norms: reduce over the 4 lq lanes (same lm -> same row)
#pragma unroll
    for (int m = 0; m < 4; ++m) {
        na[m] += __shfl_xor(na[m], 16); na[m] += __shfl_xor(na[m], 32);
        nb[m] += __shfl_xor(nb[m], 16); nb[m] += __shfl_xor(nb[m], 32);
    }
    if (expw && lq == 0) {                         // export D (rows ra..ra+63)
#pragma unroll
        for (int m = 0; m < 4; ++m) ws[WS_D + b * DIM + ra + 16 * m + lm] = na[m];
    }

    const float scale = expf(tsc[0]);
    float rp[4][4] = {}, cp[4] = {};
#pragma unroll
    for (int m = 0; m < 4; ++m) {
        float di_[4];
#pragma unroll
        for (int r = 0; r < 4; ++r) di_[r] = __shfl(na[m], 4 * lq + r);  // row 16m+4lq+r
#pragma unroll
        for (int n = 0; n < 4; ++n) {
            const float djn = nb[n];               // col row 16n+lm = own lane
#pragma unroll
            for (int p = 0; p < 4; ++p) {
                float v = __builtin_amdgcn_sqrtf(
                    fmaf(scale, fmaxf(fmaf(-2.f, acc[m][n][p], di_[p] + djn), 0.f), EPSV));
                rp[m][p] += v; cp[n] += v;
            }
        }
    }

    __syncthreads();   // sRow/sCol zero-init visible before LDS atomics
#pragma unroll
    for (int m = 0; m < 4; ++m)
#pragma unroll
        for (int p = 0; p < 4; ++p) {
            float v = rp[m][p];
            v += __shfl_xor(v, 1); v += __shfl_xor(v, 2);
            v += __shfl_xor(v, 4); v += __shfl_xor(v, 8);
            if (lm == 0) atomicAdd(&sRow[r0 + 16 * m + 4 * lq + p], v);
        }
#pragma unroll
    for (int n = 0; n < 4; ++n) {
        float v = cp[n];
        v += __shfl_xor(v, 16); v += __shfl_xor(v, 32);
        if (lq == 0) atomicAdd(&sCol[c0 + 16 * n + lm], v);
    }
    __syncthreads();

    // slot-addressed partial stores (no atomics, no zero-init) — R9-verified.
    // Tile t's 5 slots: rows from pairs (t,tj>=t) at slot tj; cols from
    // (ti<t,t) at slot ti -> bijective coverage.
    float* sp = ws + WS_SP;
    if (tid < BT) {
        sp[((b * 5 + ti) * 5 + tj) * 128 + tid] = sRow[tid];
        if (!diag)
            sp[((b * 5 + tj) * 5 + ti) * 128 + tid] = sCol[tid];
    }
    if (tid < 64) {
        float gg = sRow[tid] + sRow[tid + 64];
        gg += __shfl_xor(gg, 1);  gg += __shfl_xor(gg, 2);  gg += __shfl_xor(gg, 4);
        gg += __shfl_xor(gg, 8);  gg += __shfl_xor(gg, 16); gg += __shfl_xor(gg, 32);
        if (tid == 0) ws[WS_GP + b * 15 + u] = (diag ? 1.f : 2.f) * gg;
    }
}

// Pass 2: wave-independent 32x32 tiles (R10) + barrier-free per-wave S/G
// partial reduction. No LDS, no barriers anywhere.
__global__ __launch_bounds__(256) void k_write(const float* __restrict__ tsc,
                                               const float* __restrict__ ws,
                                               float* __restrict__ out) {
    const int tid = threadIdx.x;
    const int wave = tid >> 6, lane = tid & 63;
    const int lm = lane & 15, lq = lane >> 4;

    const int bid = blockIdx.x;
    const int xcd = bid & 7;
    const int idx = bid >> 3;              // 0..423
    const int b = xcd + 8 * (idx & 7);     // fixed set of 8 batches per XCD
    const int pr = (idx >> 3) * 4 + wave;  // 0..211
    if (pr >= NPAIRW) return;              // dummy slot (wave-uniform)
    int ti, tj;
    decode_pairN<NTW>(pr, ti, tj);
    const int i0 = ti * WT, j0 = tj * WT;

    // per-wave S reduction: lane l owns index (l<32 ? row i0+l : col j0+l-32)
    float Sv;
    {
        const int ix = (lane < 32) ? (i0 + lane) : (j0 + (lane - 32));
        const float* p = ws + WS_SP + (size_t)((b * 5 + (ix >> 7)) * 5) * 128
                         + (ix & 127);
        Sv = p[0] + p[128] + p[256] + p[384] + p[512];
    }
    float gv = (lane < 15) ? ws[WS_GP + b * 15 + lane] : 0.f;
    gv += __shfl_xor(gv, 1);  gv += __shfl_xor(gv, 2);  gv += __shfl_xor(gv, 4);
    gv += __shfl_xor(gv, 8);  gv += __shfl_xor(gv, 16); gv += __shfl_xor(gv, 32);

    const short* xb = (const short*)((const char*)ws + XB_OFF);
    const short* pa = xb + (size_t)(b * 40 + 2 * ti) * 2048 + lq * 128 + lm * 8;
    const short* pb = xb + (size_t)(b * 40 + 2 * tj) * 2048 + lq * 128 + lm * 8;

    f32x4 acc[2][2] = {};
#pragma unroll
    for (int ks = 0; ks < 4; ++ks) {
        short8 a0 = *(const short8*)(pa + ks * 512);
        short8 a1 = *(const short8*)(pa + 2048 + ks * 512);
        short8 b0 = *(const short8*)(pb + ks * 512);
        short8 b1 = *(const short8*)(pb + 2048 + ks * 512);
        acc[0][0] = __builtin_amdgcn_mfma_f32_16x16x32_bf16(a0, b0, acc[0][0], 0, 0, 0);
        acc[0][1] = __builtin_amdgcn_mfma_f32_16x16x32_bf16(a0, b1, acc[0][1], 0, 0, 0);
        acc[1][0] = __builtin_amdgcn_mfma_f32_16x16x32_bf16(a1, b0, acc[1][0], 0, 0, 0);
        acc[1][1] = __builtin_amdgcn_mfma_f32_16x16x32_bf16(a1, b1, acc[1][1], 0, 0, 0);
    }

    const float scale = expf(tsc[0]);
    const float inv = 1.f / (float)DIM;
    const float g = gv * (inv * inv);
    const float* dn = ws + WS_D + b * DIM;

    const bool pred = (ti == tj);          // predicated upper-tri on diag tiles
    float di[2][4], ai[2][4]; int ib[2][4];
#pragma unroll
    for (int m = 0; m < 2; ++m)
#pragma unroll
        for (int r = 0; r < 4; ++r) {
            int i = i0 + 16 * m + 4 * lq + r;
            di[m][r] = dn[i];
            ai[m][r] = g - __shfl(Sv, 16 * m + 4 * lq + r) * inv;
            ib[m][r] = i * DIM - (i * (i - 1)) / 2 - i;   // triu row offset minus i
        }
    float dj[2], bj[2]; int jj[2];
#pragma unroll
    for (int n = 0; n < 2; ++n) {
        int j = j0 + 16 * n + lm;
        jj[n] = j; dj[n] = dn[j];
        bj[n] = -__shfl(Sv, 32 + 16 * n + lm) * inv;
    }

    float* outb = out + (size_t)b * PTRI;
#pragma unroll
    for (int m = 0; m < 2; ++m) {
        const int ibase = i0 + 16 * m + 4 * lq;
#pragma unroll
        for (int n = 0; n < 2; ++n)
#pragma unroll
            for (int p = 0; p < 2; ++p) {
                const int r = 2 * p;
                float d0 = di[m][r]     + dj[n];
                float d1 = di[m][r + 1] + dj[n];
                float v0 = __builtin_amdgcn_sqrtf(
                    fmaf(scale, fmaxf(fmaf(-2.f, acc[m][n][r],     d0), 0.f), EPSV));
                float v1 = __builtin_amdgcn_sqrtf(
                    fmaf(scale, fmaxf(fmaf(-2.f, acc[m][n][r + 1], d1), 0.f), EPSV));
                if (!pred || jj[n] >= ibase + r)
                    outb[ib[m][r]     + jj[n]] = v0 + ai[m][r]     + bj[n];
                if (!pred || jj[n] >= ibase + r + 1)
                    outb[ib[m][r + 1] + jj[n]] = v1 + ai[m][r + 1] + bj[n];
            }
    }
}

extern "C" void kernel_launch(void* const* d_in, const int* in_sizes, int n_in,
                              void* d_out, int out_size, void* d_ws, size_t ws_size,
                              hipStream_t stream) {
    const float* x = (const float*)d_in[0];
    const float* t = (const float*)d_in[1];
    float* out = (float*)d_out;
    float* ws  = (float*)d_ws;   // needs ~11.5 MB (see layout at top)

    k_sums <<<dim3(NBLK2), 256, 0, stream>>>(x, t, ws);
    k_write<<<dim3(NBLKW), 256, 0, stream>>>(t, ws, out);
}

// Round 12
// 113.756 us; speedup vs baseline: 1.1957x; 1.1957x over previous
//
#include <hip/hip_runtime.h>
#include <math.h>

#define BATCH 64
#define DIM   640
#define MSP   100        // spatial M = 10*10
#define TILE  64         // k_write tile
#define NT    10         // DIM / TILE
#define NPAIR 55         // 64-tile upper-tri pairs
#define BT    128        // k_sums tile
#define NT2   5          // DIM / BT
#define NPAIR2 15        // 128-tile upper-tri pairs
#define NBLK2 960        // NPAIR2 * BATCH
#define PTRI  205120     // DIM*(DIM+1)/2
#define EPSV  1e-5f

// ws float-region offsets (floats)
#define WS_D 0
#define WS_S 40960
#define WS_G 81920            // 64 grand accumulators (raw sums)
// byte offsets (float region ends at 81984*4 = 327936, 256B-aligned)
#define XB_OFF 327936ull      // swizzled bf16 x: 2560 panels x 2048 shorts = 10,485,760 B
// total ws ~10.8 MB
//
// Lessons encoded (R0..R11):
//  - cooperative launch / host API in kernel_launch breaks graph capture (R3/R4)
//  - device spin barriers + agent-scope atomics are latency-poisoned (R7: +155us)
//  - XCD-pinning batches (bid&7=XCD, 8 batches/XCD, data < 4MB L2): ~17us (R1->R2)
//  - dispatch-merge attempts ALL lose: R9 (LDS prep fusion, +9us: 64KB LDS
//    occupancy + serial panel loop), R11 (register prep fusion, +21.5us:
//    6x dup conversion, 180 VGPR -> 9% occupancy, k_sums 52us measured)
//  - write pass latency-bound: 3520 blk > 960 blk (+10us, R6->R8); 32-tile
//    wave-items == 64-tile blocks (R10)
//  - sums tile 64 vs 128: neutral (R5/R6)
//  - ~53us harness-fixed (256MiB ws poison fill + 52MB out memset); kernel
//    pure work ~30us; remaining ~25us is inter-dispatch drain (unreachable
//    under this harness's constraints)
//
// R12 = R8 verbatim (best measured: 114.16us).

typedef __attribute__((ext_vector_type(8))) short short8;
typedef __attribute__((ext_vector_type(4))) float f32x4;

__device__ __forceinline__ short f2bf(float f) {
    union { float f; unsigned u; } x; x.f = f;
    unsigned r = x.u + 0x7fffu + ((x.u >> 16) & 1u);
    return (short)(r >> 16);
}
__device__ __forceinline__ float bf2f(short h) {
    union { unsigned u; float f; } x; x.u = ((unsigned)(unsigned short)h) << 16;
    return x.f;
}

template <int NT_>
__device__ __forceinline__ void decode_pairN(int u, int& ti, int& tj) {
    ti = 0;
    while (u >= NT_ - ti) { u -= NT_ - ti; ++ti; }
    tj = ti + u;
}

// bid (0..959) -> (b, ti, tj), 128-tiles, XCD-pinned batches
__device__ __forceinline__ void decode_block128(int bid, int& b, int& ti, int& tj) {
    const int xcd = bid & 7;
    const int idx = bid >> 3;          // 0..119
    b = xcd + 8 * (idx & 7);           // fixed set of 8 batches per XCD
    decode_pairN<NT2>(idx >> 3, ti, tj);
}

// bid (0..3519) -> (b, ti, tj), 64-tiles, XCD-pinned batches
__device__ __forceinline__ void decode_block64(int bid, int& b, int& ti, int& tj) {
    const int xcd = bid & 7;
    const int idx = bid >> 3;          // 0..439
    b = xcd + 8 * (idx & 7);
    decode_pairN<NT>(idx >> 3, ti, tj);
}

// One pass over x: bf16 RNE convert, K 100->128 zero-pad, store SWIZZLED xb;
// norms from ROUNDED values (diag d_i+d_i-2G_ii cancels exactly vs bf16 MFMA);
// zero S and G accumulators (ws is poisoned each call).
// xb swizzle: panel = 16 rows x 128 k, stored [c = ks*4+lq][lm = row%16][8 halves].
__global__ __launch_bounds__(256) void k_prep(const float* __restrict__ x,
                                              float* __restrict__ ws) {
    short* xb = (short*)((char*)ws + XB_OFF);
    const int t = threadIdx.x;
    const int rr = t >> 4, c = t & 15;             // rr = row-in-panel, c = k-chunk
    const int row = blockIdx.x * 16 + rr;          // 0..40959
    const int k0 = c * 8;
    const float* src = x + (size_t)row * MSP;

    float v[8];
#pragma unroll
    for (int e = 0; e < 8; ++e) v[e] = 0.f;
    if (k0 <= 88) {                                // k0..k0+7 all < 100
        float4 u0 = *(const float4*)(src + k0);
        float4 u1 = *(const float4*)(src + k0 + 4);
        v[0] = u0.x; v[1] = u0.y; v[2] = u0.z; v[3] = u0.w;
        v[4] = u1.x; v[5] = u1.y; v[6] = u1.z; v[7] = u1.w;
    } else if (k0 == 96) {                         // only 96..99 valid (no OOB read)
        float4 u0 = *(const float4*)(src + 96);
        v[0] = u0.x; v[1] = u0.y; v[2] = u0.z; v[3] = u0.w;
    }

    short8 h; float s = 0.f;
#pragma unroll
    for (int e = 0; e < 8; ++e) {
        short hb = f2bf(v[e]);
        float vr = bf2f(hb);
        s += vr * vr;
        h[e] = hb;
    }
    // swizzled store: panel base + c*128 + rr*8
    *(short8*)(xb + (size_t)blockIdx.x * 2048 + c * 128 + rr * 8) = h;

    // norm reduce over the 16 k-chunks (lanes with same rr, c = lane&15)
    s += __shfl_xor(s, 1); s += __shfl_xor(s, 2);
    s += __shfl_xor(s, 4); s += __shfl_xor(s, 8);
    if (c == 0) { ws[WS_D + row] = s; ws[WS_S + row] = 0.f; }
    if (blockIdx.x == 0 && t < BATCH) ws[WS_G + t] = 0.f;
}

// Pass 1: 128x128 tile (960 blocks). Wave (wr,wc) owns a 64x64 quadrant with
// acc[4][4] -> sqrt-dcov -> S (row sums + symmetric col fold) + grand sum.
__global__ __launch_bounds__(256) void k_sums(const float* __restrict__ tsc,
                                              float* __restrict__ ws) {
    __shared__ float sRow[BT];
    __shared__ float sCol[BT];

    int b, ti, tj;
    decode_block128(blockIdx.x, b, ti, tj);
    const int i0 = ti * BT, j0 = tj * BT;
    const int tid = threadIdx.x;
    const short* xb = (const short*)((const char*)ws + XB_OFF);

    if (tid < BT) { sRow[tid] = 0.f; sCol[tid] = 0.f; }

    const int wave = tid >> 6, lane = tid & 63;
    const int lm = lane & 15, lq = lane >> 4;
    const int r0 = (wave >> 1) * 64, c0 = (wave & 1) * 64;

    // per-lane frag pointers; panel m at +m*2048, k-step ks at +ks*512
    const short* pa = xb + (size_t)(b * 40 + ((i0 + r0) >> 4)) * 2048 + lq * 128 + lm * 8;
    const short* pb = xb + (size_t)(b * 40 + ((j0 + c0) >> 4)) * 2048 + lq * 128 + lm * 8;

    f32x4 acc[4][4] = {};
#pragma unroll
    for (int ks = 0; ks < 4; ++ks) {
        short8 af[4], bf[4];
#pragma unroll
        for (int m = 0; m < 4; ++m) af[m] = *(const short8*)(pa + m * 2048 + ks * 512);
#pragma unroll
        for (int n = 0; n < 4; ++n) bf[n] = *(const short8*)(pb + n * 2048 + ks * 512);
#pragma unroll
        for (int m = 0; m < 4; ++m)
#pragma unroll
            for (int n = 0; n < 4; ++n)
                acc[m][n] = __builtin_amdgcn_mfma_f32_16x16x32_bf16(af[m], bf[n], acc[m][n], 0, 0, 0);
    }

    const float scale = expf(tsc[0]);
    const float* dn = ws + WS_D + b * DIM;
    float dj[4];
#pragma unroll
    for (int n = 0; n < 4; ++n) dj[n] = dn[j0 + c0 + 16 * n + lm];

    float rp[4][4] = {}, cp[4] = {};
#pragma unroll
    for (int m = 0; m < 4; ++m) {
        float di_[4];
#pragma unroll
        for (int r = 0; r < 4; ++r) di_[r] = dn[i0 + r0 + 16 * m + 4 * lq + r];
#pragma unroll
        for (int n = 0; n < 4; ++n)
#pragma unroll
            for (int p = 0; p < 4; ++p) {
                float v = __builtin_amdgcn_sqrtf(
                    fmaf(scale, fmaxf(fmaf(-2.f, acc[m][n][p], di_[p] + dj[n]), 0.f), EPSV));
                rp[m][p] += v; cp[n] += v;
            }
    }

    __syncthreads();   // sRow/sCol zero-init visible before LDS atomics
#pragma unroll
    for (int m = 0; m < 4; ++m)
#pragma unroll
        for (int p = 0; p < 4; ++p) {
            float v = rp[m][p];
            v += __shfl_xor(v, 1); v += __shfl_xor(v, 2);
            v += __shfl_xor(v, 4); v += __shfl_xor(v, 8);
            if (lm == 0) atomicAdd(&sRow[r0 + 16 * m + 4 * lq + p], v);
        }
#pragma unroll
    for (int n = 0; n < 4; ++n) {
        float v = cp[n];
        v += __shfl_xor(v, 16); v += __shfl_xor(v, 32);
        if (lq == 0) atomicAdd(&sCol[c0 + 16 * n + lm], v);
    }
    __syncthreads();

    float* S = ws + WS_S + b * DIM;
    if (tid < BT) {
        atomicAdd(&S[i0 + tid], sRow[tid]);
        if (ti != tj) atomicAdd(&S[j0 + tid], sCol[tid]);  // symmetry: col==row sums
        float gg = sRow[tid];                              // per-batch grand (raw)
        gg += __shfl_xor(gg, 1);  gg += __shfl_xor(gg, 2);  gg += __shfl_xor(gg, 4);
        gg += __shfl_xor(gg, 8);  gg += __shfl_xor(gg, 16); gg += __shfl_xor(gg, 32);
        if (lane == 0) atomicAdd(&ws[WS_G + b], (ti == tj ? 1.f : 2.f) * gg);
    }
}

// Pass 2: 64-tile (3520 blocks), RECOMPUTE quadrant (frag reads = L2 hits),
// center, write triu fp32. Diagonal tiles: the below-diagonal wave quadrant
// (r0=32,c0=0) returns before any work. No LDS/barriers in this kernel.
__global__ __launch_bounds__(256) void k_write(const float* __restrict__ tsc,
                                               const float* __restrict__ ws,
                                               float* __restrict__ out) {
    int b, ti, tj;
    decode_block64(blockIdx.x, b, ti, tj);
    const int i0 = ti * TILE, j0 = tj * TILE;
    const int tid = threadIdx.x;
    const short* xb = (const short*)((const char*)ws + XB_OFF);

    const int wave = tid >> 6, lane = tid & 63;
    const int lm = lane & 15, lq = lane >> 4;
    const int wr = wave >> 1, wc = wave & 1;
    const int r0 = wr * 32, c0 = wc * 32;

    const bool diag = (ti == tj);
    if (diag && wr > wc) return;       // 32x32 quadrant fully below diagonal
    const bool pred = diag && (wr == wc);

    const short* pa = xb + (size_t)(b * 40 + ((i0 + r0) >> 4)) * 2048 + lq * 128 + lm * 8;
    const short* pb = xb + (size_t)(b * 40 + ((j0 + c0) >> 4)) * 2048 + lq * 128 + lm * 8;

    f32x4 acc[2][2] = {};
#pragma unroll
    for (int ks = 0; ks < 4; ++ks) {
        short8 a0 = *(const short8*)(pa + ks * 512);
        short8 a1 = *(const short8*)(pa + 2048 + ks * 512);
        short8 b0 = *(const short8*)(pb + ks * 512);
        short8 b1 = *(const short8*)(pb + 2048 + ks * 512);
        acc[0][0] = __builtin_amdgcn_mfma_f32_16x16x32_bf16(a0, b0, acc[0][0], 0, 0, 0);
        acc[0][1] = __builtin_amdgcn_mfma_f32_16x16x32_bf16(a0, b1, acc[0][1], 0, 0, 0);
        acc[1][0] = __builtin_amdgcn_mfma_f32_16x16x32_bf16(a1, b0, acc[1][0], 0, 0, 0);
        acc[1][1] = __builtin_amdgcn_mfma_f32_16x16x32_bf16(a1, b1, acc[1][1], 0, 0, 0);
    }

    const float scale = expf(tsc[0]);
    const float inv = 1.f / (float)DIM;
    const float g = ws[WS_G + b] * (inv * inv);
    const float* S  = ws + WS_S + b * DIM;
    const float* dn = ws + WS_D + b * DIM;

    float di[2][4], ai[2][4]; int ib[2][4];
#pragma unroll
    for (int a = 0; a < 2; ++a)
#pragma unroll
        for (int r = 0; r < 4; ++r) {
            int i = i0 + r0 + 16 * a + 4 * lq + r;
            di[a][r] = dn[i];
            ai[a][r] = g - S[i] * inv;
            ib[a][r] = i * DIM - (i * (i - 1)) / 2 - i;   // triu row offset minus i
        }
    float dj[2], bj[2]; int jj[2];
#pragma unroll
    for (int bb = 0; bb < 2; ++bb) {
        int j = j0 + c0 + 16 * bb + lm;
        jj[bb] = j; dj[bb] = dn[j]; bj[bb] = -S[j] * inv;
    }

    float* outb = out + (size_t)b * PTRI;
#pragma unroll
    for (int a = 0; a < 2; ++a) {
        const int ibase = i0 + r0 + 16 * a + 4 * lq;
#pragma unroll
        for (int bb = 0; bb < 2; ++bb)
#pragma unroll
            for (int p = 0; p < 2; ++p) {
                const int r = 2 * p;
                float d0 = di[a][r]     + dj[bb];
                float d1 = di[a][r + 1] + dj[bb];
                float v0 = __builtin_amdgcn_sqrtf(
                    fmaf(scale, fmaxf(fmaf(-2.f, acc[a][bb][r],     d0), 0.f), EPSV));
                float v1 = __builtin_amdgcn_sqrtf(
                    fmaf(scale, fmaxf(fmaf(-2.f, acc[a][bb][r + 1], d1), 0.f), EPSV));
                if (!pred || jj[bb] >= ibase + r)
                    outb[ib[a][r]     + jj[bb]] = v0 + ai[a][r]     + bj[bb];
                if (!pred || jj[bb] >= ibase + r + 1)
                    outb[ib[a][r + 1] + jj[bb]] = v1 + ai[a][r + 1] + bj[bb];
            }
    }
}

extern "C" void kernel_launch(void* const* d_in, const int* in_sizes, int n_in,
                              void* d_out, int out_size, void* d_ws, size_t ws_size,
                              hipStream_t stream) {
    const float* x = (const float*)d_in[0];
    const float* t = (const float*)d_in[1];
    float* out = (float*)d_out;
    float* ws  = (float*)d_ws;   // needs ~10.8 MB (see layout at top)

    k_prep <<<dim3(BATCH * DIM / 16), 256, 0, stream>>>(x, ws);
    k_sums <<<dim3(NBLK2),            256, 0, stream>>>(t, ws);
    k_write<<<dim3(NPAIR * BATCH),    256, 0, stream>>>(t, ws, out);
}